// Round 15
// baseline (89.140 us; speedup 1.0000x reference)
//
#include <hip/hip_runtime.h>

// Conv1dFFT via polyphase: y[b] = IFFT_8192( sum_p G_p * FFT_8192(x_polyphase_p) )
// R12 structure (86us best) with:
//  - stage-1 loads batched (R12 form, no inner fences -> keep MLP)
//  - accumulate loop: float4 P/Q loads (64B/thread contiguous), fence per c-pair
//  - single merged build kernel (g_W + P/Q) -> one fewer launch per call

#define TK      8192
#define LOG2TK  13
#define HALF_TK 4096
#define KFOLD   8
#define NPAIR   4
#define TFULL   65536
#define NT      1024
#define RSQ2    0.70710678118654752440f

// LDS bank-conflict swizzle (bijective: low 4 bits XOR bits 4..7)
#define SW(i) ((i) ^ (((i) >> 4) & 15))

// Compiler-only ordering fence for wave-synchronous LDS hand-offs.
#define WAVE_SYNC() do { asm volatile("" ::: "memory"); __builtin_amdgcn_wave_barrier(); } while (0)
// Scheduling fence: bounds register live ranges (R12-proven).
#define SCHED_FENCE() __builtin_amdgcn_sched_barrier(0)

__device__ __forceinline__ float2 cmul(float2 a, float2 b) {
    return make_float2(a.x * b.x - a.y * b.y, a.x * b.y + a.y * b.x);
}
__device__ __forceinline__ unsigned br13(unsigned r) { return __brev(r) >> 19u; }

__device__ float2 g_W[HALF_TK];        // e^{-2pi i t/8192}
__device__ float2 g_P[NPAIR * TK];     // bit-reversed order
__device__ float2 g_Q[NPAIR * TK];     // bit-reversed order

// Merged build: g_W (t<4096) + P/Q (all t). P/Q doesn't read g_W -> fusable.
__global__ void build_tables_kernel(const float* __restrict__ filt) {
    int t = blockIdx.x * blockDim.x + threadIdx.x;
    if (t >= TK) return;
    if (t < HALF_TK) {
        float ang = -6.28318530717958647693f * (float)t / (float)TK;
        float c, s;
        __sincosf(ang, &s, &c);
        g_W[t] = make_float2(c, s);
    }
    const float c8[8] = { 1.f,  RSQ2,  0.f, -RSQ2, -1.f, -RSQ2,  0.f,  RSQ2 };
    const float s8[8] = { 0.f, -RSQ2, -1.f, -RSQ2,  0.f,  RSQ2,  1.f,  RSQ2 };
    float fm[KFOLD];
#pragma unroll
    for (int m = 0; m < KFOLD; ++m) fm[m] = filt[m * TK + t];
    float2 G[KFOLD];
#pragma unroll
    for (int p = 0; p < KFOLD; ++p) {
        float sr = 0.f, si = 0.f;
#pragma unroll
        for (int m = 0; m < KFOLD; ++m) {
            int k = (p * m) & 7;
            sr += fm[m] * c8[k];
            si += fm[m] * s8[k];
        }
        float ang2 = -6.28318530717958647693f * (float)(p * t) / (float)TFULL;
        float c2, s2;
        __sincosf(ang2, &s2, &c2);
        G[p] = make_float2((sr * c2 - si * s2) * 0.125f,
                           (sr * s2 + si * c2) * 0.125f);
    }
    const float norm = 0.5f / (float)TK;
    unsigned r = br13((unsigned)t);
#pragma unroll
    for (int j = 0; j < NPAIR; ++j) {
        float2 g0 = G[2 * j], g1 = G[2 * j + 1];
        g_P[j * TK + r] = make_float2((g0.x + g1.y) * norm, (g0.y - g1.x) * norm);
        g_Q[j * TK + r] = make_float2((g0.x - g1.y) * norm, (g0.y + g1.x) * norm);
    }
}

// Forward DIF radix-8 pass: stages (4s, 2s, s), s = 1<<C.
template<int C>
__device__ __forceinline__ void fwd_pass(float2* buf, int tid) {
    const int s = 1 << C;
    const int q0 = tid & (s - 1);
    const int i0 = ((tid >> C) << (C + 3)) + q0;
    float2 e[8];
#pragma unroll
    for (int t = 0; t < 8; ++t) e[t] = buf[SW(i0 + t * s)];
    float2 w1, w2, w3;
    if (C == 0) { w1 = make_float2(1.f, 0.f); w2 = w1; w3 = w1; }
    else { w1 = g_W[q0 << (10 - C)]; w2 = cmul(w1, w1); w3 = cmul(w2, w2); }
#pragma unroll
    for (int t = 0; t < 4; ++t) {
        float2 a = e[t], b = e[t + 4];
        float2 d = make_float2(a.x - b.x, a.y - b.y);
        e[t] = make_float2(a.x + b.x, a.y + b.y);
        d = cmul(d, w1);
        if (t == 1)      d = make_float2(RSQ2 * (d.x + d.y), RSQ2 * (d.y - d.x));
        else if (t == 2) d = make_float2(d.y, -d.x);
        else if (t == 3) d = make_float2(RSQ2 * (d.y - d.x), -RSQ2 * (d.x + d.y));
        e[t + 4] = d;
    }
#pragma unroll
    for (int t0 = 0; t0 < 8; t0 += 4) {
#pragma unroll
        for (int t = 0; t < 2; ++t) {
            int i = t0 + t;
            float2 a = e[i], b = e[i + 2];
            float2 d = make_float2(a.x - b.x, a.y - b.y);
            e[i] = make_float2(a.x + b.x, a.y + b.y);
            d = cmul(d, w2);
            if (t == 1) d = make_float2(d.y, -d.x);
            e[i + 2] = d;
        }
    }
#pragma unroll
    for (int t = 0; t < 8; t += 2) {
        float2 a = e[t], b = e[t + 1];
        float2 d = make_float2(a.x - b.x, a.y - b.y);
        e[t] = make_float2(a.x + b.x, a.y + b.y);
        e[t + 1] = cmul(d, w3);
    }
#pragma unroll
    for (int t = 0; t < 8; ++t) buf[SW(i0 + t * s)] = e[t];
}

// Inverse DIT radix-8 pass: stages (s, 2s, 4s), conjugated twiddles.
template<int C>
__device__ __forceinline__ void inv_pass(float2* buf, int tid) {
    const int s = 1 << C;
    const int q0 = tid & (s - 1);
    const int i0 = ((tid >> C) << (C + 3)) + q0;
    float2 e[8];
#pragma unroll
    for (int t = 0; t < 8; ++t) e[t] = buf[SW(i0 + t * s)];
    float2 v1, v2, v3;
    if (C == 0) { v1 = make_float2(1.f, 0.f); v2 = v1; v3 = v1; }
    else { v1 = g_W[q0 << (10 - C)]; v1.y = -v1.y; v2 = cmul(v1, v1); v3 = cmul(v2, v2); }
#pragma unroll
    for (int t = 0; t < 8; t += 2) {
        float2 b = cmul(e[t + 1], v3);
        float2 a = e[t];
        e[t]     = make_float2(a.x + b.x, a.y + b.y);
        e[t + 1] = make_float2(a.x - b.x, a.y - b.y);
    }
#pragma unroll
    for (int t0 = 0; t0 < 8; t0 += 4) {
#pragma unroll
        for (int t = 0; t < 2; ++t) {
            int i = t0 + t;
            float2 b = cmul(e[i + 2], v2);
            if (t == 1) b = make_float2(-b.y, b.x);
            float2 a = e[i];
            e[i]     = make_float2(a.x + b.x, a.y + b.y);
            e[i + 2] = make_float2(a.x - b.x, a.y - b.y);
        }
    }
#pragma unroll
    for (int t = 0; t < 4; ++t) {
        float2 b = cmul(e[t + 4], v1);
        if (t == 1)      b = make_float2(RSQ2 * (b.x - b.y), RSQ2 * (b.x + b.y));
        else if (t == 2) b = make_float2(-b.y, b.x);
        else if (t == 3) b = make_float2(-RSQ2 * (b.x + b.y), RSQ2 * (b.x - b.y));
        float2 a = e[t];
        e[t]     = make_float2(a.x + b.x, a.y + b.y);
        e[t + 4] = make_float2(a.x - b.x, a.y - b.y);
    }
#pragma unroll
    for (int t = 0; t < 8; ++t) buf[SW(i0 + t * s)] = e[t];
}

// Accumulate 8 y_hat points (r = 8*tid + c) from one buffer with float4 P/Q
// loads (thread's 8 float2 = 64 contiguous bytes) and a fence per c-pair.
__device__ __forceinline__ void acc_from(const float2* buf, int tid,
                                         const float2* __restrict__ P,
                                         const float2* __restrict__ Q,
                                         float2* acc) {
    const float4* __restrict__ P4 = reinterpret_cast<const float4*>(P);
    const float4* __restrict__ Q4 = reinterpret_cast<const float4*>(Q);
#pragma unroll
    for (int cp = 0; cp < 4; ++cp) {
        int r0 = 8 * tid + 2 * cp;
        float4 Pv = P4[4 * tid + cp];     // P[r0], P[r0+1]
        float4 Qv = Q4[4 * tid + cp];     // Q[r0], Q[r0+1]
#pragma unroll
        for (int k = 0; k < 2; ++k) {
            int r = r0 + k;
            unsigned t = br13((unsigned)r);
            unsigned tm = (TK - t) & (TK - 1);
            int r2 = (int)br13(tm);
            float2 Zt = buf[SW(r)];
            float2 Zm = buf[SW(r2)];
            float2 Pc = k ? make_float2(Pv.z, Pv.w) : make_float2(Pv.x, Pv.y);
            float2 Qc = k ? make_float2(Qv.z, Qv.w) : make_float2(Qv.x, Qv.y);
            acc[2 * cp + k].x += Zt.x * Pc.x - Zt.y * Pc.y + Zm.x * Qc.x + Zm.y * Qc.y;
            acc[2 * cp + k].y += Zt.x * Pc.y + Zt.y * Pc.x + Zm.x * Qc.y - Zm.y * Qc.x;
        }
        SCHED_FENCE();
    }
}

__global__ __launch_bounds__(NT, 4)   // (1024,4): proven VGPR=64 allocator mode
void conv_fft_kernel(const float* __restrict__ x, float2* __restrict__ out) {
    __shared__ float2 smem[2 * TK];           // 128 KB static: two 8192-pt buffers
    float2* bufA = smem;
    float2* bufB = smem + TK;
    const int tid = threadIdx.x;
    const int b = blockIdx.x;
    const float4* __restrict__ xrow4 =
        reinterpret_cast<const float4*>(x + (size_t)b * TFULL);

    float2 acc[8];
#pragma unroll
    for (int c = 0; c < 8; ++c) acc[c] = make_float2(0.f, 0.f);

    for (int jp = 0; jp < 2; ++jp) {          // FFT pair: j = 2jp (A), 2jp+1 (B)
        // global float4 load fused with first DIF stage (h = 4096), both buffers
        // (R12 form: batched loads, no inner fences -> memory-level parallelism)
#pragma unroll
        for (int c4 = 0; c4 < 4; ++c4) {
            int u = c4 * NT + tid;
            float4 a  = xrow4[2 * u + jp];                 // (reA,imA,reB,imB) @ u
            float4 b2 = xrow4[2 * (u + HALF_TK) + jp];     // @ u+4096
            float2 w = g_W[u];
            bufA[SW(u)] = make_float2(a.x + b2.x, a.y + b2.y);
            bufA[SW(u + HALF_TK)] = cmul(make_float2(a.x - b2.x, a.y - b2.y), w);
            bufB[SW(u)] = make_float2(a.z + b2.z, a.w + b2.w);
            bufB[SW(u + HALF_TK)] = cmul(make_float2(a.z - b2.z, a.w - b2.w), w);
        }
        __syncthreads();
        fwd_pass<9>(bufA, tid); SCHED_FENCE(); fwd_pass<9>(bufB, tid);
        __syncthreads();
        // C6 -> C3 -> C0 communicate only within a wave: compiler fence only
        fwd_pass<6>(bufA, tid); SCHED_FENCE(); fwd_pass<6>(bufB, tid);
        WAVE_SYNC();
        fwd_pass<3>(bufA, tid); SCHED_FENCE(); fwd_pass<3>(bufB, tid);
        WAVE_SYNC();
        fwd_pass<0>(bufA, tid); SCHED_FENCE(); fwd_pass<0>(bufB, tid);
        __syncthreads();
        // accumulate at r = 8*tid + c: y_hat += Z*P + conj(Z[-t])*Q
        acc_from(bufA, tid, g_P + (size_t)(2 * jp) * TK,
                            g_Q + (size_t)(2 * jp) * TK, acc);
        SCHED_FENCE();
        acc_from(bufB, tid, g_P + (size_t)(2 * jp + 1) * TK,
                            g_Q + (size_t)(2 * jp + 1) * TK, acc);
        __syncthreads();
    }

    // First inverse radix-8 pass (C=0, unit twiddles) in registers:
    // thread tid owns y_hat_br[8*tid .. 8*tid+8) == acc[0..8)  (validated R5)
    {
        float2 e[8];
#pragma unroll
        for (int t = 0; t < 8; t += 2) {
            float2 a = acc[t], bb = acc[t + 1];
            e[t]     = make_float2(a.x + bb.x, a.y + bb.y);
            e[t + 1] = make_float2(a.x - bb.x, a.y - bb.y);
        }
#pragma unroll
        for (int t0 = 0; t0 < 8; t0 += 4) {
            {
                float2 a = e[t0], bb = e[t0 + 2];
                e[t0]     = make_float2(a.x + bb.x, a.y + bb.y);
                e[t0 + 2] = make_float2(a.x - bb.x, a.y - bb.y);
            }
            {
                float2 a = e[t0 + 1], bb = e[t0 + 3];
                bb = make_float2(-bb.y, bb.x);
                e[t0 + 1] = make_float2(a.x + bb.x, a.y + bb.y);
                e[t0 + 3] = make_float2(a.x - bb.x, a.y - bb.y);
            }
        }
#pragma unroll
        for (int t = 0; t < 4; ++t) {
            float2 bb = e[t + 4];
            if (t == 1)      bb = make_float2(RSQ2 * (bb.x - bb.y), RSQ2 * (bb.x + bb.y));
            else if (t == 2) bb = make_float2(-bb.y, bb.x);
            else if (t == 3) bb = make_float2(-RSQ2 * (bb.x + bb.y), RSQ2 * (bb.x - bb.y));
            float2 a = e[t];
            e[t]     = make_float2(a.x + bb.x, a.y + bb.y);
            e[t + 4] = make_float2(a.x - bb.x, a.y - bb.y);
        }
#pragma unroll
        for (int t = 0; t < 8; ++t) bufA[SW(8 * tid + t)] = e[t];
    }
    WAVE_SYNC();
    // C0 -> C3 -> C6 same-wave; barrier before the cross-wave C9
    inv_pass<3>(bufA, tid);
    WAVE_SYNC();
    inv_pass<6>(bufA, tid);
    __syncthreads();
    inv_pass<9>(bufA, tid);
    __syncthreads();
    // final DIT stage (h = 4096) fused with global store
    float2* __restrict__ orow = out + (size_t)b * TK;
#pragma unroll
    for (int c4 = 0; c4 < 4; ++c4) {
        int u = c4 * NT + tid;
        float2 a = bufA[SW(u)];
        float2 w = g_W[u]; w.y = -w.y;
        float2 bb = cmul(bufA[SW(u + HALF_TK)], w);
        orow[u]           = make_float2(a.x + bb.x, a.y + bb.y);
        orow[u + HALF_TK] = make_float2(a.x - bb.x, a.y - bb.y);
    }
}

extern "C" void kernel_launch(void* const* d_in, const int* in_sizes, int n_in,
                              void* d_out, int out_size, void* d_ws, size_t ws_size,
                              hipStream_t stream) {
    const float* x    = (const float*)d_in[0];
    const float* filt = (const float*)d_in[1];
    const int T = in_sizes[1];          // 65536
    const int B = in_sizes[0] / T;      // 256 rows
    (void)n_in; (void)d_ws; (void)ws_size; (void)out_size; (void)T;

    build_tables_kernel<<<TK / 256, 256, 0, stream>>>(filt);
    conv_fft_kernel<<<B, NT, 0, stream>>>(x, (float2*)d_out);
}